// Round 1
// baseline (5614.128 us; speedup 1.0000x reference)
//
#include <hip/hip_runtime.h>
#include <math.h>

typedef __attribute__((ext_vector_type(8))) short short8;
typedef __attribute__((ext_vector_type(4))) float floatx4;

__device__ __forceinline__ unsigned short f2b(float f) {
  unsigned u = __builtin_bit_cast(unsigned, f);
  u += 0x7fffu + ((u >> 16) & 1u);
  return (unsigned short)(u >> 16);
}
__device__ __forceinline__ float b2f(unsigned short h) {
  unsigned u = ((unsigned)h) << 16;
  return __builtin_bit_cast(float, u);
}

// ---------------------------------------------------------------------------
// GEMM: C[M,N] (op)= A[M,K] @ B
//   A: bf16, row index remapped: row = (m/adiv)*amul + aoff + m%adiv
//   B: BT==0 -> K x N (BDT==0: fp32 converted to bf16 in staging; BDT==1: bf16)
//      BT==1 -> N x K bf16 (i.e. computes A @ B^T)
//   CMODE: 0 store bf16, 1 store f32, 2 accumulate into f32 (C += )
//   batch: off = (z/zdiv)*Z1 + (z%zdiv)*Z2 per operand (element offsets)
// Requirements: K % 32 == 0, N % 64 == 0 (only M may be ragged).
// ---------------------------------------------------------------------------
template<int BDT, int BT, int CMODE>
__global__ __launch_bounds__(256) void gemm_k(
    const unsigned short* __restrict__ A, int lda, int adiv, int amul, int aoff,
    const void* __restrict__ Bp, int ldb,
    void* __restrict__ Cp, int ldc, int cdiv, int cmul, int coff,
    int M, int K, int zdiv,
    long long aZ1, long long aZ2, long long bZ1, long long bZ2,
    long long cZ1, long long cZ2)
{
  __shared__ alignas(16) unsigned short As[64][40];  // [m][k], stride 40 (80B, 16B-aligned rows)
  __shared__ alignas(16) unsigned short Bs[64][40];  // [n][k]

  const int z  = blockIdx.z;
  const int zq = z / zdiv, zr = z % zdiv;
  const unsigned short* Ab = A + zq * aZ1 + zr * aZ2;
  const long long boff  = zq * bZ1 + zr * bZ2;
  const long long coffz = zq * cZ1 + zr * cZ2;

  const int m0 = blockIdx.y * 64, n0 = blockIdx.x * 64;
  const int tid  = threadIdx.x;
  const int wave = tid >> 6, lane = tid & 63;
  const int lm = lane & 15, lq = lane >> 4;

  floatx4 acc[4] = {};

  // A staging: thread -> (row sm, 8 k's at sk8)
  const int sm  = tid >> 2;
  const int sk8 = (tid & 3) << 3;
  int amg = m0 + sm; if (amg >= M) amg = M - 1;
  const long long arow = (long long)(amg / adiv) * amul + aoff + (amg % adiv);
  const unsigned short* aptr = Ab + arow * (long long)lda + sk8;

  for (int k0 = 0; k0 < K; k0 += 32) {
    *(uint4*)&As[sm][sk8] = *(const uint4*)(aptr + k0);

    if (BT == 1) {
      const unsigned short* Bb = (const unsigned short*)Bp + boff;
      *(uint4*)&Bs[sm][sk8] =
          *(const uint4*)(Bb + (long long)(n0 + sm) * ldb + k0 + sk8);
    } else {
      const int kk = tid >> 3;          // 0..31
      const int n8 = (tid & 7) << 3;    // 0,8,...,56
      if (BDT == 0) {
        const float* Bb = (const float*)Bp + boff;
        const float* src = Bb + (long long)(k0 + kk) * ldb + n0 + n8;
        const float4 v0 = *(const float4*)(src);
        const float4 v1 = *(const float4*)(src + 4);
        Bs[n8 + 0][kk] = f2b(v0.x); Bs[n8 + 1][kk] = f2b(v0.y);
        Bs[n8 + 2][kk] = f2b(v0.z); Bs[n8 + 3][kk] = f2b(v0.w);
        Bs[n8 + 4][kk] = f2b(v1.x); Bs[n8 + 5][kk] = f2b(v1.y);
        Bs[n8 + 6][kk] = f2b(v1.z); Bs[n8 + 7][kk] = f2b(v1.w);
      } else {
        const unsigned short* Bb = (const unsigned short*)Bp + boff;
        const ushort4* src = (const ushort4*)(Bb + (long long)(k0 + kk) * ldb + n0 + n8);
        const ushort4 v0 = src[0], v1 = src[1];
        Bs[n8 + 0][kk] = v0.x; Bs[n8 + 1][kk] = v0.y;
        Bs[n8 + 2][kk] = v0.z; Bs[n8 + 3][kk] = v0.w;
        Bs[n8 + 4][kk] = v1.x; Bs[n8 + 5][kk] = v1.y;
        Bs[n8 + 6][kk] = v1.z; Bs[n8 + 7][kk] = v1.w;
      }
    }
    __syncthreads();

    const short8 af = *(const short8*)&As[wave * 16 + lm][lq * 8];
#pragma unroll
    for (int s = 0; s < 4; ++s) {
      const short8 bf = *(const short8*)&Bs[s * 16 + lm][lq * 8];
      acc[s] = __builtin_amdgcn_mfma_f32_16x16x32_bf16(af, bf, acc[s], 0, 0, 0);
    }
    __syncthreads();
  }

#pragma unroll
  for (int r = 0; r < 4; ++r) {
    const int mg = m0 + wave * 16 + lq * 4 + r;
    if (mg >= M) continue;
    const long long crow = (long long)(mg / cdiv) * cmul + coff + (mg % cdiv);
#pragma unroll
    for (int s = 0; s < 4; ++s) {
      const int ng = n0 + s * 16 + lm;
      const float v = acc[s][r];
      const long long idx = coffz + crow * (long long)ldc + ng;
      if (CMODE == 0)      ((unsigned short*)Cp)[idx] = f2b(v);
      else if (CMODE == 1) ((float*)Cp)[idx] = v;
      else                 ((float*)Cp)[idx] += v;
    }
  }
}

// ---------------------------------------------------------------------------
// concat prefix/suffix (fp32) into unified X = d_out, rows b*818 + t
// ---------------------------------------------------------------------------
__global__ __launch_bounds__(256) void concat_k(
    const float* __restrict__ pre, const float* __restrict__ suf, float* __restrict__ X)
{
  const long long i = (long long)blockIdx.x * 256 + threadIdx.x;  // float4 index
  const long long total = (long long)4 * 818 * 512;
  if (i >= total) return;
  const int c  = (int)(i & 511);
  const int rr = (int)(i >> 9);
  const int bb = rr / 818, t = rr % 818;
  const float4* src = (t < 768)
      ? ((const float4*)pre + ((long long)bb * 768 + t) * 512 + c)
      : ((const float4*)suf + ((long long)bb * 50 + (t - 768)) * 512 + c);
  ((float4*)X)[i] = *src;
}

// ---------------------------------------------------------------------------
// RMSNorm: X fp32 (B*L,2048) -> bf16, weight (1+w), w picked by stream
// ---------------------------------------------------------------------------
__global__ __launch_bounds__(256) void rmsnorm_k(
    const float* __restrict__ X, const float* __restrict__ wpre,
    const float* __restrict__ wsuf, unsigned short* __restrict__ out)
{
  const int r = blockIdx.x;
  const int t = r % 818;
  const float* w = (t < 768) ? wpre : wsuf;
  const float* x = X + (long long)r * 2048;
  const int tid = threadIdx.x;

  const float4 v0 = *(const float4*)(x + tid * 4);
  const float4 v1 = *(const float4*)(x + 1024 + tid * 4);
  float ss = v0.x*v0.x + v0.y*v0.y + v0.z*v0.z + v0.w*v0.w
           + v1.x*v1.x + v1.y*v1.y + v1.z*v1.z + v1.w*v1.w;
  for (int o = 32; o > 0; o >>= 1) ss += __shfl_down(ss, o);
  __shared__ float red[4];
  if ((tid & 63) == 0) red[tid >> 6] = ss;
  __syncthreads();
  const float mean = (red[0] + red[1] + red[2] + red[3]) * (1.0f / 2048.0f);
  const float rs = rsqrtf(mean + 1e-6f);

  const float4 w0 = *(const float4*)(w + tid * 4);
  const float4 w1 = *(const float4*)(w + 1024 + tid * 4);
  ushort4 o0, o1;
  o0.x = f2b(v0.x * rs * (1.0f + w0.x));
  o0.y = f2b(v0.y * rs * (1.0f + w0.y));
  o0.z = f2b(v0.z * rs * (1.0f + w0.z));
  o0.w = f2b(v0.w * rs * (1.0f + w0.w));
  o1.x = f2b(v1.x * rs * (1.0f + w1.x));
  o1.y = f2b(v1.y * rs * (1.0f + w1.y));
  o1.z = f2b(v1.z * rs * (1.0f + w1.z));
  o1.w = f2b(v1.w * rs * (1.0f + w1.w));
  *(ushort4*)(out + (long long)r * 2048 + tid * 4) = o0;
  *(ushort4*)(out + (long long)r * 2048 + 1024 + tid * 4) = o1;
}

// ---------------------------------------------------------------------------
// RoPE in place on Q (B*L,8,256) and K (B,832,256) bf16
// ---------------------------------------------------------------------------
__global__ __launch_bounds__(256) void rope_k(
    unsigned short* __restrict__ Q, unsigned short* __restrict__ K,
    const int* __restrict__ pos_ids)
{
  const int r = blockIdx.x;              // b*818 + t
  const int b = r / 818, t = r % 818;
  const int tid = threadIdx.x;
  __shared__ float cs[128], sn[128];
  if (tid < 128) {
    const float inv = expf(-(float)tid * (9.210340371976184f / 128.0f)); // 10000^(-d/128)
    const float f = (float)pos_ids[r] * inv;
    cs[tid] = cosf(f);
    sn[tid] = sinf(f);
  }
  __syncthreads();
  unsigned short* qr = Q + (long long)r * 2048;
  unsigned short* kr = K + ((long long)b * 832 + t) * 256;
  for (int w = tid; w < 9 * 128; w += 256) {
    const int h = w >> 7, d = w & 127;
    unsigned short* base = (h < 8) ? (qr + h * 256) : kr;
    const float a = b2f(base[d]), bb = b2f(base[d + 128]);
    base[d]       = f2b(a * cs[d] - bb * sn[d]);
    base[d + 128] = f2b(bb * cs[d] + a * sn[d]);
  }
}

// ---------------------------------------------------------------------------
// masked softmax: S fp32 (B,H,818,832) -> P bf16 (same layout, pads zeroed)
// mask: allow = (k < 768) || (k <= q); scale = HD^-0.5 = 1/16
// ---------------------------------------------------------------------------
__global__ __launch_bounds__(256) void softmax_k(
    const float* __restrict__ S, unsigned short* __restrict__ P)
{
  const long long r = blockIdx.x;        // b*H*818 + h*818 + q
  const int q = (int)(r % 818);
  const float* s = S + r * 832;
  unsigned short* p = P + r * 832;
  const int tid = threadIdx.x;

  float vals[4];
  float mx = -3.0e38f;
#pragma unroll
  for (int i = 0; i < 4; ++i) {
    const int k = tid + i * 256;
    float v = -3.0e38f;
    if (k < 818 && ((k < 768) || (k <= q))) v = s[k] * 0.0625f;
    vals[i] = v;
    mx = fmaxf(mx, v);
  }
  for (int o = 32; o > 0; o >>= 1) mx = fmaxf(mx, __shfl_down(mx, o));
  __shared__ float red[4];
  if ((tid & 63) == 0) red[tid >> 6] = mx;
  __syncthreads();
  mx = fmaxf(fmaxf(red[0], red[1]), fmaxf(red[2], red[3]));
  __syncthreads();

  float sum = 0.f;
#pragma unroll
  for (int i = 0; i < 4; ++i) {
    const float e = __expf(vals[i] - mx);
    vals[i] = e;
    sum += e;
  }
  for (int o = 32; o > 0; o >>= 1) sum += __shfl_down(sum, o);
  if ((tid & 63) == 0) red[tid >> 6] = sum;
  __syncthreads();
  const float inv = 1.0f / (red[0] + red[1] + red[2] + red[3]);

#pragma unroll
  for (int i = 0; i < 4; ++i) {
    const int k = tid + i * 256;
    if (k < 832) p[k] = (k < 818) ? f2b(vals[i] * inv) : (unsigned short)0;
  }
}

// ---------------------------------------------------------------------------
// G = gelu_tanh(G) * U   (bf16, vectorized x4)
// ---------------------------------------------------------------------------
__global__ __launch_bounds__(256) void gelumul_k(
    ushort4* __restrict__ G, const ushort4* __restrict__ U, int n4)
{
  const int i = blockIdx.x * 256 + threadIdx.x;
  if (i >= n4) return;
  const ushort4 g4 = G[i], u4 = U[i];
  ushort4 o;
  {
    const float g = b2f(g4.x), u = b2f(u4.x);
    o.x = f2b(0.5f * g * (1.0f + tanhf(0.7978845608f * (g + 0.044715f * g * g * g))) * u);
  }
  {
    const float g = b2f(g4.y), u = b2f(u4.y);
    o.y = f2b(0.5f * g * (1.0f + tanhf(0.7978845608f * (g + 0.044715f * g * g * g))) * u);
  }
  {
    const float g = b2f(g4.z), u = b2f(u4.z);
    o.z = f2b(0.5f * g * (1.0f + tanhf(0.7978845608f * (g + 0.044715f * g * g * g))) * u);
  }
  {
    const float g = b2f(g4.w), u = b2f(u4.w);
    o.w = f2b(0.5f * g * (1.0f + tanhf(0.7978845608f * (g + 0.044715f * g * g * g))) * u);
  }
  G[i] = o;
}

// ---------------------------------------------------------------------------
extern "C" void kernel_launch(void* const* d_in, const int* in_sizes, int n_in,
                              void* d_out, int out_size, void* d_ws, size_t ws_size,
                              hipStream_t stream)
{
  const float* prefix  = (const float*)d_in[0];
  const float* suffix  = (const float*)d_in[1];
  const int*   pos_ids = (const int*)d_in[3];
  const float* p_ln1 = (const float*)d_in[4];
  const float* p_q   = (const float*)d_in[5];
  const float* p_k   = (const float*)d_in[6];
  const float* p_v   = (const float*)d_in[7];
  const float* p_o   = (const float*)d_in[8];
  const float* p_ln2 = (const float*)d_in[9];
  const float* p_g   = (const float*)d_in[10];
  const float* p_u   = (const float*)d_in[11];
  const float* p_d   = (const float*)d_in[12];
  const float* e_ln1 = (const float*)d_in[13];
  const float* e_q   = (const float*)d_in[14];
  const float* e_k   = (const float*)d_in[15];
  const float* e_v   = (const float*)d_in[16];
  const float* e_o   = (const float*)d_in[17];
  const float* e_ln2 = (const float*)d_in[18];
  const float* e_g   = (const float*)d_in[19];
  const float* e_u   = (const float*)d_in[20];
  const float* e_d   = (const float*)d_in[21];

  const int IDENT = 1073741824;  // identity row map: div huge, mul 0, off 0

  float* X = (float*)d_out;  // residual stream (B*818, 2048) fp32 == final output

  char* w = (char*)d_ws;
  unsigned short* Nb  = (unsigned short*)w; w += (size_t)3272 * 2048 * 2;
  unsigned short* Qb  = (unsigned short*)w; w += (size_t)3272 * 2048 * 2;
  unsigned short* Kb  = (unsigned short*)w; w += (size_t)4 * 832 * 256 * 2;
  unsigned short* Vb  = (unsigned short*)w; w += (size_t)4 * 832 * 256 * 2;
  unsigned short* Att = (unsigned short*)w; w += (size_t)3272 * 2048 * 2;
  char* R = w;                                        // reused region
  float*          Sb = (float*)R;                     // scores  (B,H,818,832) f32
  unsigned short* Pb = (unsigned short*)(R + (size_t)4 * 8 * 818 * 832 * 4);
  unsigned short* Gb = (unsigned short*)R;            // MLP gate (reuses S/P region)
  unsigned short* Ub = (unsigned short*)(R + (size_t)(3072 * 8192 + 200 * 4096) * 2);

  concat_k<<<6544, 256, 0, stream>>>(prefix, suffix, X);

  for (int l = 0; l < 2; ++l) {
    const size_t oQ = (size_t)l * 2048 * 2048;
    const size_t oK = (size_t)l * 2048 * 256;
    const size_t oG = (size_t)l * 2048 * 8192;
    const size_t oGe = (size_t)l * 2048 * 4096;
    const size_t oD = (size_t)l * 8192 * 2048;
    const size_t oDe = (size_t)l * 4096 * 2048;
    const size_t oL = (size_t)l * 2048;

    // ---- rmsnorm 1 ----
    rmsnorm_k<<<3272, 256, 0, stream>>>(X, p_ln1 + oL, e_ln1 + oL, Nb);

    // ---- QKV projections (prefix rows: map (768,818,0); suffix: (50,818,768)) ----
    gemm_k<0,0,0><<<dim3(32,48,1), 256, 0, stream>>>(Nb, 2048, 768, 818, 0,
        p_q + oQ, 2048, Qb, 2048, 768, 818, 0, 3072, 2048, 1, 0,0,0,0,0,0);
    gemm_k<0,0,0><<<dim3(32,4,1), 256, 0, stream>>>(Nb, 2048, 50, 818, 768,
        e_q + oQ, 2048, Qb, 2048, 50, 818, 768, 200, 2048, 1, 0,0,0,0,0,0);
    gemm_k<0,0,0><<<dim3(4,48,1), 256, 0, stream>>>(Nb, 2048, 768, 818, 0,
        p_k + oK, 256, Kb, 256, 768, 832, 0, 3072, 2048, 1, 0,0,0,0,0,0);
    gemm_k<0,0,0><<<dim3(4,4,1), 256, 0, stream>>>(Nb, 2048, 50, 818, 768,
        e_k + oK, 256, Kb, 256, 50, 832, 768, 200, 2048, 1, 0,0,0,0,0,0);
    gemm_k<0,0,0><<<dim3(4,48,1), 256, 0, stream>>>(Nb, 2048, 768, 818, 0,
        p_v + oK, 256, Vb, 256, 768, 832, 0, 3072, 2048, 1, 0,0,0,0,0,0);
    gemm_k<0,0,0><<<dim3(4,4,1), 256, 0, stream>>>(Nb, 2048, 50, 818, 768,
        e_v + oK, 256, Vb, 256, 50, 832, 768, 200, 2048, 1, 0,0,0,0,0,0);

    // ---- RoPE ----
    rope_k<<<3272, 256, 0, stream>>>(Qb, Kb, pos_ids);

    // ---- scores = Q @ K^T  (per b,h) ----
    gemm_k<1,1,1><<<dim3(13,13,32), 256, 0, stream>>>(
        Qb, 2048, IDENT, 0, 0, Kb, 256, Sb, 832, IDENT, 0, 0,
        818, 256, 8,
        (long long)818*2048, 256,            // A: +b*L*2048 + h*256
        (long long)832*256, 0,               // B: +b*832*256
        (long long)8*818*832, (long long)818*832);  // C: +z*818*832

    // ---- softmax ----
    softmax_k<<<4 * 8 * 818, 256, 0, stream>>>(Sb, Pb);

    // ---- att = P @ V  (per b,h) ----
    gemm_k<1,0,0><<<dim3(4,13,32), 256, 0, stream>>>(
        Pb, 832, IDENT, 0, 0, Vb, 256, Att, 2048, IDENT, 0, 0,
        818, 832, 8,
        (long long)8*818*832, (long long)818*832,
        (long long)832*256, 0,
        (long long)818*2048, 256);

    // ---- O projection, accumulate into residual X ----
    gemm_k<0,0,2><<<dim3(32,48,1), 256, 0, stream>>>(Att, 2048, 768, 818, 0,
        p_o + oQ, 2048, X, 2048, 768, 818, 0, 3072, 2048, 1, 0,0,0,0,0,0);
    gemm_k<0,0,2><<<dim3(32,4,1), 256, 0, stream>>>(Att, 2048, 50, 818, 768,
        e_o + oQ, 2048, X, 2048, 50, 818, 768, 200, 2048, 1, 0,0,0,0,0,0);

    // ---- rmsnorm 2 ----
    rmsnorm_k<<<3272, 256, 0, stream>>>(X, p_ln2 + oL, e_ln2 + oL, Nb);

    // ---- MLP gate / up ----
    gemm_k<0,0,0><<<dim3(128,48,1), 256, 0, stream>>>(Nb, 2048, 768, 818, 0,
        p_g + oG, 8192, Gb, 8192, IDENT, 0, 0, 3072, 2048, 1, 0,0,0,0,0,0);
    gemm_k<0,0,0><<<dim3(64,4,1), 256, 0, stream>>>(Nb, 2048, 50, 818, 768,
        e_g + oGe, 4096, Gb + (size_t)3072*8192, 4096, IDENT, 0, 0, 200, 2048, 1, 0,0,0,0,0,0);
    gemm_k<0,0,0><<<dim3(128,48,1), 256, 0, stream>>>(Nb, 2048, 768, 818, 0,
        p_u + oG, 8192, Ub, 8192, IDENT, 0, 0, 3072, 2048, 1, 0,0,0,0,0,0);
    gemm_k<0,0,0><<<dim3(64,4,1), 256, 0, stream>>>(Nb, 2048, 50, 818, 768,
        e_u + oGe, 4096, Ub + (size_t)3072*8192, 4096, IDENT, 0, 0, 200, 2048, 1, 0,0,0,0,0,0);

    // ---- gelu(gate) * up ----
    gelumul_k<<<25376, 256, 0, stream>>>((ushort4*)Gb, (const ushort4*)Ub,
                                         (3072 * 8192 + 200 * 4096) / 4);

    // ---- down projection, accumulate into residual X ----
    gemm_k<0,0,2><<<dim3(32,48,1), 256, 0, stream>>>(Gb, 8192, IDENT, 0, 0,
        p_d + oD, 2048, X, 2048, 768, 818, 0, 3072, 8192, 1, 0,0,0,0,0,0);
    gemm_k<0,0,2><<<dim3(32,4,1), 256, 0, stream>>>(Gb + (size_t)3072*8192, 4096, IDENT, 0, 0,
        e_d + oDe, 2048, X, 2048, 50, 818, 768, 200, 4096, 1, 0,0,0,0,0,0);
  }
  (void)in_sizes; (void)n_in; (void)out_size; (void)ws_size;
}